// Round 1
// baseline (59.361 us; speedup 1.0000x reference)
//
#include <hip/hip_runtime.h>

#define NN   4096
#define TWON 8192
#define DD   256
#define TINV 2.0f
#define SCALE 1.69864363f   // sqrt(log2(e)/T), T=0.5
#define CS   16             // column splits in main kernel

typedef __attribute__((ext_vector_type(8)))  short v8s;
typedef __attribute__((ext_vector_type(16))) float v16f;

__device__ inline unsigned short f2bf(float f) {
  unsigned int u = __float_as_uint(f);
  u += 0x7FFFu + ((u >> 16) & 1u);
  return (unsigned short)(u >> 16);
}

// K1: normalize rows of z=concat(zi,zj), scale by sqrt(log2e/T), store bf16 + norms
__global__ void k_normalize(const float* __restrict__ zi, const float* __restrict__ zj,
                            unsigned short* __restrict__ zn, float* __restrict__ norms) {
  int wid = threadIdx.x >> 6, lane = threadIdx.x & 63;
  int row = blockIdx.x * 4 + wid;
  const float* src = (row < NN) ? (zi + (size_t)row * DD) : (zj + (size_t)(row - NN) * DD);
  float4 v = *(const float4*)(src + lane * 4);
  float ss = v.x*v.x + v.y*v.y + v.z*v.z + v.w*v.w;
  #pragma unroll
  for (int m = 1; m < 64; m <<= 1) ss += __shfl_xor(ss, m, 64);
  float nrm = fmaxf(sqrtf(ss), 1e-8f);
  if (lane == 0) norms[row] = nrm;
  float sc = SCALE / nrm;
  ushort4 o;
  o.x = f2bf(v.x * sc); o.y = f2bf(v.y * sc);
  o.z = f2bf(v.z * sc); o.w = f2bf(v.w * sc);
  *(ushort4*)(zn + (size_t)row * DD + lane * 4) = o;
}

// K2: partial sums of pos_k = dot(zi[k],zj[k])/(ni*nj)/T ; 256 blocks
__global__ void k_pos(const float* __restrict__ zi, const float* __restrict__ zj,
                      const float* __restrict__ norms, float* __restrict__ pospart) {
  int tid = threadIdx.x, wid = tid >> 6, lane = tid & 63;
  float acc = 0.f;
  #pragma unroll
  for (int p = 0; p < 4; ++p) {
    int k = blockIdx.x * 16 + wid * 4 + p;
    float4 a = *(const float4*)(zi + (size_t)k * DD + lane * 4);
    float4 b = *(const float4*)(zj + (size_t)k * DD + lane * 4);
    float d = a.x*b.x + a.y*b.y + a.z*b.z + a.w*b.w;
    #pragma unroll
    for (int m = 1; m < 64; m <<= 1) d += __shfl_xor(d, m, 64);
    if (lane == 0) acc += d * TINV / (norms[k] * norms[NN + k]);
  }
  __shared__ float sb[4];
  if (lane == 0) sb[wid] = acc;
  __syncthreads();
  if (tid == 0) pospart[blockIdx.x] = (sb[0] + sb[1]) + (sb[2] + sb[3]);
}

// K3: main. Each block: 256 rows (4 waves x 64 rows), 512-col slice, tiles of 32 cols.
// acc holds sim*log2e/T; accumulate exp2(acc) per row; diagonal zeroed.
__global__ __launch_bounds__(256, 2) void k_main(const unsigned short* __restrict__ zn,
                                                 float* __restrict__ wsum) {
  const char* znb = (const char*)zn;
  int tid = threadIdx.x, wid = tid >> 6, lane = tid & 63;
  int rb = blockIdx.x >> 4, cs = blockIdx.x & 15;
  int wrow0 = rb * 256 + wid * 64;
  int lr = lane & 31, lg = lane >> 5;

  // A fragments: 64 rows x 256 K in registers (2 row-halves x 16 K-steps)
  v8s afrag[2][16];
  #pragma unroll
  for (int h = 0; h < 2; ++h) {
    #pragma unroll
    for (int kk = 0; kk < 16; ++kk) {
      size_t off = (size_t)(wrow0 + h * 32 + lr) * 512 + kk * 32 + lg * 16;
      afrag[h][kk] = *(const v8s*)(znb + off);
    }
  }

  __shared__ char tile[16384];   // 32 cols' vectors: 32 x 512B
  v16f sumv0, sumv1;
  #pragma unroll
  for (int q = 0; q < 16; ++q) { sumv0[q] = 0.f; sumv1[q] = 0.f; }

  int cbase = cs * 512;
  for (int ct = 0; ct < 16; ++ct) {
    int ctile = cbase + ct * 32;
    // stage 16KB tile: linear LDS dest, pre-swizzled global source (XOR (row&15)<<4)
    #pragma unroll
    for (int p = 0; p < 4; ++p) {
      int X = p * 4096 + tid * 16;
      int rl = X >> 9;
      int colb = X & 511;
      const char* src = znb + (size_t)(ctile + rl) * 512 + (colb ^ ((rl & 15) << 4));
      __builtin_amdgcn_global_load_lds((const __attribute__((address_space(1))) void*)src,
                                       (__attribute__((address_space(3))) void*)&tile[p * 4096 + wid * 1024],
                                       16, 0, 0);
    }
    __syncthreads();

    v16f acc0, acc1;
    #pragma unroll
    for (int q = 0; q < 16; ++q) { acc0[q] = 0.f; acc1[q] = 0.f; }
    #pragma unroll
    for (int kk = 0; kk < 16; ++kk) {
      int colb = (kk * 32 + (lg << 4)) ^ ((lr & 15) << 4);
      v8s b = *(const v8s*)&tile[lr * 512 + colb];
      acc0 = __builtin_amdgcn_mfma_f32_32x32x16_bf16(afrag[0][kk], b, acc0, 0, 0, 0);
      acc1 = __builtin_amdgcn_mfma_f32_32x32x16_bf16(afrag[1][kk], b, acc1, 0, 0, 0);
    }

    bool d0 = (ctile == wrow0);
    bool d1 = (ctile == wrow0 + 32);
    #pragma unroll
    for (int q = 0; q < 16; ++q) {
      int row_off = 4 * lg + (q & 3) + 8 * (q >> 2);
      float e0 = exp2f(acc0[q]);
      float e1 = exp2f(acc1[q]);
      if (d0 && row_off == lr) e0 = 0.f;
      if (d1 && row_off == lr) e1 = 0.f;
      sumv0[q] += e0;
      sumv1[q] += e1;
    }
    __syncthreads();
  }

  // reduce across the 32 columns held by each 32-lane group
  #pragma unroll
  for (int q = 0; q < 16; ++q) {
    float v0 = sumv0[q], v1 = sumv1[q];
    #pragma unroll
    for (int m = 1; m < 32; m <<= 1) {
      v0 += __shfl_xor(v0, m, 64);
      v1 += __shfl_xor(v1, m, 64);
    }
    sumv0[q] = v0; sumv1[q] = v1;
  }
  if (lr < 16) {
    int qi = lr;
    float o0 = 0.f, o1 = 0.f;
    #pragma unroll
    for (int q = 0; q < 16; ++q) {   // static-index extraction (avoid scratch)
      o0 = (q == qi) ? sumv0[q] : o0;
      o1 = (q == qi) ? sumv1[q] : o1;
    }
    int ro = 4 * lg + (qi & 3) + 8 * (qi >> 2);
    wsum[(size_t)(wrow0 + ro) * CS + cs] = o0;
    wsum[(size_t)(wrow0 + 32 + ro) * CS + cs] = o1;
  }
}

// K4a: per-row lse = ln(sum of 16 partials); 64 blocks x 128 rows -> block partial sums
__global__ void k_lse(const float* __restrict__ wsum, float* __restrict__ lsepart) {
  int tid = threadIdx.x;
  int row = blockIdx.x * 128 + tid;
  const float4* p = (const float4*)(wsum + (size_t)row * 16);
  float4 a = p[0], b = p[1], c = p[2], d = p[3];
  float s = (((a.x + a.y) + (a.z + a.w)) + ((b.x + b.y) + (b.z + b.w)))
          + (((c.x + c.y) + (c.z + c.w)) + ((d.x + d.y) + (d.z + d.w)));
  float lse = logf(s);
  #pragma unroll
  for (int m = 1; m < 64; m <<= 1) lse += __shfl_xor(lse, m, 64);
  __shared__ float sb[2];
  if ((tid & 63) == 0) sb[tid >> 6] = lse;
  __syncthreads();
  if (tid == 0) lsepart[blockIdx.x] = sb[0] + sb[1];
}

// K4b: final scalars
__global__ void k_final(const float* __restrict__ lsepart, const float* __restrict__ pospart,
                        float* __restrict__ out) {
  int tid = threadIdx.x, wid = tid >> 6, lane = tid & 63;
  float li = (tid < 32) ? lsepart[tid] : 0.f;
  float lj = (tid >= 32 && tid < 64) ? lsepart[tid] : 0.f;
  float pp = pospart[tid];
  #pragma unroll
  for (int m = 1; m < 64; m <<= 1) {
    li += __shfl_xor(li, m, 64);
    lj += __shfl_xor(lj, m, 64);
    pp += __shfl_xor(pp, m, 64);
  }
  __shared__ float sI[4], sJ[4], sP[4];
  if (lane == 0) { sI[wid] = li; sJ[wid] = lj; sP[wid] = pp; }
  __syncthreads();
  if (tid == 0) {
    float SI = (sI[0] + sI[1]) + (sI[2] + sI[3]);
    float SJ = (sJ[0] + sJ[1]) + (sJ[2] + sJ[3]);
    float SP = (sP[0] + sP[1]) + (sP[2] + sP[3]);
    out[0] = (SI - SP) * (1.0f / NN);
    out[1] = (SJ - SP) * (1.0f / NN);
  }
}

extern "C" void kernel_launch(void* const* d_in, const int* in_sizes, int n_in,
                              void* d_out, int out_size, void* d_ws, size_t ws_size,
                              hipStream_t stream) {
  const float* zi = (const float*)d_in[0];
  const float* zj = (const float*)d_in[1];
  float* out = (float*)d_out;
  char* ws = (char*)d_ws;
  unsigned short* zn = (unsigned short*)ws;          // 8192*256*2 = 4,194,304 B
  float* norms   = (float*)(ws + 4194304);           // 8192*4
  float* pospart = (float*)(ws + 4227072);           // 256*4
  float* lsepart = (float*)(ws + 4228096);           // 64*4
  float* wsum    = (float*)(ws + 4228352);           // 8192*16*4 = 524,288 B

  k_normalize<<<2048, 256, 0, stream>>>(zi, zj, zn, norms);
  k_pos<<<256, 256, 0, stream>>>(zi, zj, norms, pospart);
  k_main<<<512, 256, 0, stream>>>(zn, wsum);
  k_lse<<<64, 128, 0, stream>>>(wsum, lsepart);
  k_final<<<1, 256, 0, stream>>>(lsepart, pospart, out);
}

// Round 2
// 53.909 us; speedup vs baseline: 1.1011x; 1.1011x over previous
//
#include <hip/hip_runtime.h>

#define NN   4096
#define TWON 8192
#define DD   256
#define TINV 2.0f
#define SCALE 1.69864363f   // sqrt(log2(e)/T), T=0.5
#define CS   16             // column splits in main kernel

typedef __attribute__((ext_vector_type(8)))  short v8s;
typedef __attribute__((ext_vector_type(16))) float v16f;

__device__ inline unsigned short f2bf(float f) {
  unsigned int u = __float_as_uint(f);
  u += 0x7FFFu + ((u >> 16) & 1u);
  return (unsigned short)(u >> 16);
}

// K1: normalize rows of z=concat(zi,zj) -> bf16 (scaled by sqrt(log2e/T)),
// and compute pos_k = dot(zi_k,zj_k)/(|zi_k||zj_k|)/T fused via LDS.
// Block: 4 waves = {zi p0, zj p0, zi p1, zj p1}, p0=2b, p1=2b+1.
__global__ void k_normpos(const float* __restrict__ zi, const float* __restrict__ zj,
                          unsigned short* __restrict__ zn, float* __restrict__ pospart) {
  int wid = threadIdx.x >> 6, lane = threadIdx.x & 63;
  int pr  = blockIdx.x * 2 + (wid >> 1);
  int isj = wid & 1;
  const float* src = (isj ? zj : zi) + (size_t)pr * DD;
  float4 v = *(const float4*)(src + lane * 4);
  float ss = v.x*v.x + v.y*v.y + v.z*v.z + v.w*v.w;
  #pragma unroll
  for (int m = 1; m < 64; m <<= 1) ss += __shfl_xor(ss, m, 64);
  float nrm = fmaxf(sqrtf(ss), 1e-8f);

  __shared__ float zbuf[2][DD];
  __shared__ float nbuf[2];
  if (!isj) {
    *(float4*)&zbuf[wid >> 1][lane * 4] = v;
    if (lane == 0) nbuf[wid >> 1] = nrm;
  }

  float sc = SCALE / nrm;
  ushort4 o;
  o.x = f2bf(v.x * sc); o.y = f2bf(v.y * sc);
  o.z = f2bf(v.z * sc); o.w = f2bf(v.w * sc);
  int zrow = (isj ? NN : 0) + pr;
  *(ushort4*)(zn + (size_t)zrow * DD + lane * 4) = o;

  __syncthreads();
  if (isj) {
    float4 a = *(const float4*)&zbuf[wid >> 1][lane * 4];
    float d = a.x*v.x + a.y*v.y + a.z*v.z + a.w*v.w;
    #pragma unroll
    for (int m = 1; m < 64; m <<= 1) d += __shfl_xor(d, m, 64);
    if (lane == 0) pospart[pr] = d * TINV / (nbuf[wid >> 1] * nrm);
  }
}

// K3: main. Block: 256 rows (4 waves x 64), 512-col slice, tiles of 32 cols.
// B tile staged k-major in LDS: addr = kblk*512 + col*16 (kblk = 16B block of K).
// Double-buffered, stage(t+1) issued before compute(t), one barrier per tile.
__global__ __launch_bounds__(256, 2) void k_main(const unsigned short* __restrict__ zn,
                                                 float* __restrict__ wsum) {
  const char* znb = (const char*)zn;
  int tid = threadIdx.x, wid = tid >> 6, lane = tid & 63;
  int rb = blockIdx.x >> 4, cs = blockIdx.x & 15;
  int wrow0 = rb * 256 + wid * 64;
  int lr = lane & 31, lg = lane >> 5;
  int cbase = cs * 512;
  int lane_src = lr * 512 + lg * 16;   // per-lane global offset for staging

  // A fragments: 64 rows x 256 K in registers (2 row-halves x 16 K-steps)
  v8s afrag[2][16];
  #pragma unroll
  for (int h = 0; h < 2; ++h) {
    #pragma unroll
    for (int kk = 0; kk < 16; ++kk) {
      size_t off = (size_t)(wrow0 + h * 32 + lr) * 512 + kk * 32 + lg * 16;
      afrag[h][kk] = *(const v8s*)(znb + off);
    }
  }

  __shared__ char tile0[16384];
  __shared__ char tile1[16384];
  v16f sumv0, sumv1;
  #pragma unroll
  for (int q = 0; q < 16; ++q) { sumv0[q] = 0.f; sumv1[q] = 0.f; }

#define STAGE(CT, BUF) { \
    size_t gb = (size_t)(cbase + (CT) * 32) * 512; \
    _Pragma("unroll") \
    for (int p = 0; p < 4; ++p) { \
      int t = wid * 4 + p; \
      const char* s = znb + gb + t * 32 + lane_src; \
      __builtin_amdgcn_global_load_lds((const __attribute__((address_space(1))) void*)s, \
          (__attribute__((address_space(3))) void*)&(BUF)[t * 1024], 16, 0, 0); \
    } }

#define COMPUTE(BUF, CT) { \
    int ctile = cbase + (CT) * 32; \
    v16f acc0, acc1; \
    _Pragma("unroll") \
    for (int q = 0; q < 16; ++q) { acc0[q] = 0.f; acc1[q] = 0.f; } \
    const char* bb = &(BUF)[lg * 512 + lr * 16]; \
    _Pragma("unroll") \
    for (int kk = 0; kk < 16; ++kk) { \
      v8s b = *(const v8s*)(bb + kk * 1024); \
      acc0 = __builtin_amdgcn_mfma_f32_32x32x16_bf16(afrag[0][kk], b, acc0, 0, 0, 0); \
      acc1 = __builtin_amdgcn_mfma_f32_32x32x16_bf16(afrag[1][kk], b, acc1, 0, 0, 0); \
    } \
    if (ctile == wrow0 || ctile == wrow0 + 32) { \
      bool h0 = (ctile == wrow0); \
      _Pragma("unroll") \
      for (int q = 0; q < 16; ++q) { \
        int ro = 4 * lg + (q & 3) + 8 * (q >> 2); \
        float e0 = __builtin_amdgcn_exp2f(acc0[q]); \
        float e1 = __builtin_amdgcn_exp2f(acc1[q]); \
        if (h0 && ro == lr) e0 = 0.f; \
        if (!h0 && ro == lr) e1 = 0.f; \
        sumv0[q] += e0; sumv1[q] += e1; \
      } \
    } else { \
      _Pragma("unroll") \
      for (int q = 0; q < 16; ++q) { \
        sumv0[q] += __builtin_amdgcn_exp2f(acc0[q]); \
        sumv1[q] += __builtin_amdgcn_exp2f(acc1[q]); \
      } \
    } }

  STAGE(0, tile0);
  __syncthreads();
  for (int c2 = 0; c2 < 8; ++c2) {
    int ctB = c2 * 2 + 1;
    STAGE(ctB, tile1);
    COMPUTE(tile0, c2 * 2);
    __syncthreads();
    if (ctB + 1 < 16) STAGE(ctB + 1, tile0);
    COMPUTE(tile1, ctB);
    __syncthreads();
  }
#undef STAGE
#undef COMPUTE

  // reduce across the 32 columns held by each 32-lane group
  #pragma unroll
  for (int q = 0; q < 16; ++q) {
    float v0 = sumv0[q], v1 = sumv1[q];
    #pragma unroll
    for (int m = 1; m < 32; m <<= 1) {
      v0 += __shfl_xor(v0, m, 64);
      v1 += __shfl_xor(v1, m, 64);
    }
    sumv0[q] = v0; sumv1[q] = v1;
  }
  if (lr < 16) {
    int qi = lr;
    float o0 = 0.f, o1 = 0.f;
    #pragma unroll
    for (int q = 0; q < 16; ++q) {   // static-index extraction (avoid scratch)
      o0 = (q == qi) ? sumv0[q] : o0;
      o1 = (q == qi) ? sumv1[q] : o1;
    }
    int ro = 4 * lg + (qi & 3) + 8 * (qi >> 2);
    wsum[(size_t)(wrow0 + ro) * CS + cs] = o0;
    wsum[(size_t)(wrow0 + 32 + ro) * CS + cs] = o1;
  }
}

// K4a: per-row lse = ln(sum of 16 partials); 64 blocks x 128 rows -> block partials
__global__ void k_lse(const float* __restrict__ wsum, float* __restrict__ lsepart) {
  int tid = threadIdx.x;
  int row = blockIdx.x * 128 + tid;
  const float4* p = (const float4*)(wsum + (size_t)row * 16);
  float4 a = p[0], b = p[1], c = p[2], d = p[3];
  float s = (((a.x + a.y) + (a.z + a.w)) + ((b.x + b.y) + (b.z + b.w)))
          + (((c.x + c.y) + (c.z + c.w)) + ((d.x + d.y) + (d.z + d.w)));
  float lse = logf(s);
  #pragma unroll
  for (int m = 1; m < 64; m <<= 1) lse += __shfl_xor(lse, m, 64);
  __shared__ float sb[2];
  if ((tid & 63) == 0) sb[tid >> 6] = lse;
  __syncthreads();
  if (tid == 0) lsepart[blockIdx.x] = sb[0] + sb[1];
}

// K4b: final scalars
__global__ void k_final(const float* __restrict__ lsepart, const float* __restrict__ pospart,
                        float* __restrict__ out) {
  int tid = threadIdx.x, wid = tid >> 6, lane = tid & 63;
  float li = (tid < 32) ? lsepart[tid] : 0.f;
  float lj = (tid >= 32 && tid < 64) ? lsepart[tid] : 0.f;
  float pp = 0.f;
  #pragma unroll
  for (int k = 0; k < 16; ++k) pp += pospart[tid + 256 * k];
  #pragma unroll
  for (int m = 1; m < 64; m <<= 1) {
    li += __shfl_xor(li, m, 64);
    lj += __shfl_xor(lj, m, 64);
    pp += __shfl_xor(pp, m, 64);
  }
  __shared__ float sI[4], sJ[4], sP[4];
  if (lane == 0) { sI[wid] = li; sJ[wid] = lj; sP[wid] = pp; }
  __syncthreads();
  if (tid == 0) {
    float SI = (sI[0] + sI[1]) + (sI[2] + sI[3]);
    float SJ = (sJ[0] + sJ[1]) + (sJ[2] + sJ[3]);
    float SP = (sP[0] + sP[1]) + (sP[2] + sP[3]);
    out[0] = (SI - SP) * (1.0f / NN);
    out[1] = (SJ - SP) * (1.0f / NN);
  }
}

extern "C" void kernel_launch(void* const* d_in, const int* in_sizes, int n_in,
                              void* d_out, int out_size, void* d_ws, size_t ws_size,
                              hipStream_t stream) {
  const float* zi = (const float*)d_in[0];
  const float* zj = (const float*)d_in[1];
  float* out = (float*)d_out;
  char* ws = (char*)d_ws;
  unsigned short* zn = (unsigned short*)ws;          // 8192*256*2 = 4,194,304 B
  float* pospart = (float*)(ws + 4194304);           // 4096*4
  float* lsepart = (float*)(ws + 4210688);           // 64*4
  float* wsum    = (float*)(ws + 4210944);           // 8192*16*4 = 524,288 B

  k_normpos<<<2048, 256, 0, stream>>>(zi, zj, zn, pospart);
  k_main<<<512, 256, 0, stream>>>(zn, wsum);
  k_lse<<<64, 128, 0, stream>>>(wsum, lsepart);
  k_final<<<1, 256, 0, stream>>>(lsepart, pospart, out);
}